// Round 1
// baseline (427.557 us; speedup 1.0000x reference)
//
#include <hip/hip_runtime.h>
#include <math.h>

// Problem constants (fixed by reference setup_inputs)
namespace {
constexpr int Bn = 4;     // batch
constexpr int Cn = 64;    // in channels
constexpr int On = 64;    // out channels
constexpr int Hn = 128;
constexpr int Wn = 128;
constexpr int Kn = 9;     // 3x3 taps
constexpr int HWn = Hn * Wn;          // 16384
constexpr int CKn = Cn * Kn;          // 576
constexpr int NPIX = Bn * HWn;        // 65536
}

// ---------------------------------------------------------------------------
// Prep: transpose weights so hot loops read contiguous wave-uniform rows
//   wt   [(c*9+k)*64 + o]  = weight[o*576 + c*9 + k]   (36864 elems)
//   wtoff[(c*9+k)*18 + j]  = w_off [j*576 + c*9 + k]   (10368 elems)
// ---------------------------------------------------------------------------
__global__ __launch_bounds__(256) void prep_transpose(
    const float* __restrict__ w_off, const float* __restrict__ weight,
    float* __restrict__ wtoff, float* __restrict__ wt) {
  int t = blockIdx.x * 256 + threadIdx.x;
  if (t < On * CKn) {
    int o = t & 63, ck = t >> 6;
    wt[t] = weight[o * CKn + ck];
  }
  if (t < 18 * CKn) {
    int j = t % 18, ck = t / 18;
    wtoff[t] = w_off[j * CKn + ck];
  }
}

// ---------------------------------------------------------------------------
// Offset conv: Conv2d(64 -> 18, 3x3, pad 1). One thread per output pixel,
// 18 accumulators. Weight reads are wave-uniform -> scalar loads.
// offset layout written: [B][18][H][W] (channel 2k = dy_k, 2k+1 = dx_k)
// ---------------------------------------------------------------------------
__global__ __launch_bounds__(256) void offset_conv(
    const float* __restrict__ x, const float* __restrict__ wtoff,
    const float* __restrict__ b_off, float* __restrict__ offset) {
  int pix = blockIdx.x * 256 + threadIdx.x;  // 65536 total
  int b = pix >> 14;
  int rem = pix & (HWn - 1);
  int y = rem >> 7;
  int xx = rem & (Wn - 1);

  float acc[18];
#pragma unroll
  for (int j = 0; j < 18; ++j) acc[j] = b_off[j];

  const float* xb = x + (size_t)b * Cn * HWn;
  for (int c = 0; c < Cn; ++c) {
    const float* plane = xb + c * HWn;
    const float* wrow = wtoff + c * (Kn * 18);
#pragma unroll
    for (int k = 0; k < Kn; ++k) {
      const int dy = k / 3 - 1, dx = k % 3 - 1;
      int yy = y + dy, xc = xx + dx;
      float v = 0.f;
      if (yy >= 0 && yy < Hn && xc >= 0 && xc < Wn) v = plane[yy * Wn + xc];
#pragma unroll
      for (int j = 0; j < 18; ++j) acc[j] = fmaf(v, wrow[k * 18 + j], acc[j]);
    }
  }

  float* ob = offset + (size_t)b * 18 * HWn + y * Wn + xx;
#pragma unroll
  for (int j = 0; j < 18; ++j) ob[j * HWn] = acc[j];
}

// ---------------------------------------------------------------------------
// Main DCN: one thread per output pixel, 64 output accumulators.
// k outer (tap params in ~9 regs), c inner: 1 bilinear sample + 64 FMAs
// against a scalar-loaded contiguous weight row wt[(c*9+k)*64 ..].
// Out-of-bounds corners contribute zero (mask folded into corner weights).
// ---------------------------------------------------------------------------
__global__ __launch_bounds__(256) void dcn_main(
    const float* __restrict__ x, const float* __restrict__ offset,
    const float* __restrict__ wt, float* __restrict__ out) {
  int pix = blockIdx.x * 256 + threadIdx.x;  // 65536 total
  int b = pix >> 14;
  int rem = pix & (HWn - 1);
  int y = rem >> 7;
  int xx = rem & (Wn - 1);

  const float* xb = x + (size_t)b * Cn * HWn;
  const float* offb = offset + (size_t)b * 18 * HWn + y * Wn + xx;

  float acc[64];
#pragma unroll
  for (int o = 0; o < 64; ++o) acc[o] = 0.f;

  for (int k = 0; k < Kn; ++k) {
    const int dy = k / 3 - 1, dx = k % 3 - 1;
    float py = (float)(y + dy) + offb[(2 * k) * HWn];
    float px = (float)(xx + dx) + offb[(2 * k + 1) * HWn];

    float y0f = floorf(py), x0f = floorf(px);
    int y0 = (int)y0f, x0 = (int)x0f;
    int y1 = y0 + 1, x1 = x0 + 1;
    float wy1 = py - y0f, wx1 = px - x0f;
    float wy0 = 1.f - wy1, wx0 = 1.f - wx1;

    // validity masks folded into the bilinear weights
    float my0 = (y0 >= 0 && y0 < Hn) ? 1.f : 0.f;
    float my1 = (y1 >= 0 && y1 < Hn) ? 1.f : 0.f;
    float mx0 = (x0 >= 0 && x0 < Wn) ? 1.f : 0.f;
    float mx1 = (x1 >= 0 && x1 < Wn) ? 1.f : 0.f;
    float w00 = wy0 * wx0 * my0 * mx0;
    float w01 = wy0 * wx1 * my0 * mx1;
    float w10 = wy1 * wx0 * my1 * mx0;
    float w11 = wy1 * wx1 * my1 * mx1;

    // clamped linear offsets (masked corners read a valid addr, weight 0)
    int cy0 = min(max(y0, 0), Hn - 1), cy1 = min(max(y1, 0), Hn - 1);
    int cx0 = min(max(x0, 0), Wn - 1), cx1 = min(max(x1, 0), Wn - 1);
    int l00 = cy0 * Wn + cx0, l01 = cy0 * Wn + cx1;
    int l10 = cy1 * Wn + cx0, l11 = cy1 * Wn + cx1;

    for (int c = 0; c < Cn; ++c) {
      const float* plane = xb + c * HWn;
      float v = w00 * plane[l00] + w01 * plane[l01] +
                w10 * plane[l10] + w11 * plane[l11];
      const float* wr = wt + (c * Kn + k) * 64;  // wave-uniform -> s_load
#pragma unroll
      for (int o = 0; o < 64; ++o) acc[o] = fmaf(v, wr[o], acc[o]);
    }
  }

  float* ob = out + (size_t)b * On * HWn + y * Wn + xx;
#pragma unroll
  for (int o = 0; o < 64; ++o) ob[o * HWn] = acc[o];  // coalesced per o
}

// ---------------------------------------------------------------------------
extern "C" void kernel_launch(void* const* d_in, const int* in_sizes, int n_in,
                              void* d_out, int out_size, void* d_ws, size_t ws_size,
                              hipStream_t stream) {
  const float* x = (const float*)d_in[0];       // [4,64,128,128]
  const float* w_off = (const float*)d_in[1];   // [18,64,3,3]
  const float* b_off = (const float*)d_in[2];   // [18]
  const float* weight = (const float*)d_in[3];  // [64,64,3,3]
  float* out = (float*)d_out;                   // [4,64,128,128]

  // workspace layout (floats)
  float* offset = (float*)d_ws;                 // 4*18*16384 = 1,179,648
  float* wt = offset + (size_t)Bn * 18 * HWn;   // 36,864
  float* wtoff = wt + On * CKn;                 // 10,368

  {
    int n = On * CKn;  // 36864 covers both transposes
    prep_transpose<<<dim3((n + 255) / 256), dim3(256), 0, stream>>>(
        w_off, weight, wtoff, wt);
  }
  offset_conv<<<dim3(NPIX / 256), dim3(256), 0, stream>>>(x, wtoff, b_off,
                                                          offset);
  dcn_main<<<dim3(NPIX / 256), dim3(256), 0, stream>>>(x, offset, wt, out);
}